// Round 1
// baseline (2382.568 us; speedup 1.0000x reference)
//
#include <hip/hip_runtime.h>

#define B_    16
#define CIN_  16
#define H_    512
#define W_    512
#define COUT_ 64
#define OH_   256
#define OW_   256
#define KMAX_ 7

// ---------------------------------------------------------------------------
// Kernel 1: weight slice absmax -> scale -> fake-quant into ws (compact
// [oc][ic][k][k]), plus loss passthrough to d_out tail.
// Single block, 1024 threads. Max slice = 64*16*49 = 50176 elems.
// ---------------------------------------------------------------------------
__global__ __launch_bounds__(1024)
void wprep_kernel(const float* __restrict__ w, const float* __restrict__ loss,
                  const int* __restrict__ sp, float* __restrict__ wq,
                  float* __restrict__ loss_out)
{
    const int k  = 3 + 2 * sp[1];          // KS_LIST = [3,5,7]
    const int s0 = (KMAX_ - k) >> 1;
    const int n  = COUT_ * CIN_ * k * k;

    float m = 0.f;
    for (int i = threadIdx.x; i < n; i += 1024) {
        int c = i % k; int t = i / k; int r = t % k; t /= k;
        int ic = t & (CIN_ - 1); int oc = t >> 4;
        float v = w[((oc * CIN_ + ic) * KMAX_ + s0 + r) * KMAX_ + s0 + c];
        m = fmaxf(m, fabsf(v));
    }
#pragma unroll
    for (int off = 32; off > 0; off >>= 1) m = fmaxf(m, __shfl_xor(m, off));

    __shared__ float sm[16];
    if ((threadIdx.x & 63) == 0) sm[threadIdx.x >> 6] = m;
    __syncthreads();
    if (threadIdx.x == 0) {
        float mm = sm[0];
#pragma unroll
        for (int i = 1; i < 16; ++i) mm = fmaxf(mm, sm[i]);
        sm[0] = mm / 127.0f;               // scale, IEEE div matches jax
    }
    __syncthreads();
    const float scale = sm[0];

    for (int i = threadIdx.x; i < n; i += 1024) {
        int c = i % k; int t = i / k; int r = t % k; t /= k;
        int ic = t & (CIN_ - 1); int oc = t >> 4;
        float v = w[((oc * CIN_ + ic) * KMAX_ + s0 + r) * KMAX_ + s0 + c];
        float q = rintf(v / scale);        // ties-to-even == jnp.round
        q = fminf(127.f, fmaxf(-127.f, q));
        wq[i] = q * scale;
    }

    if (threadIdx.x == 0) loss_out[0] = loss[0];
}

// ---------------------------------------------------------------------------
// Kernel 2: direct conv (stride 2) + fused BN/bias/leaky/bias epilogue.
// Block = 256 threads = 4 waves; each wave = one output row (256 px);
// each lane computes 4 consecutive ow via 2 aligned float4 loads + edge
// scalars. Weights for this oc staged in LDS (broadcast reads).
// Logical block order: oc fastest (64 blocks share x rows), then rowblk,
// then b; bijective XCD swizzle keeps each sharing-group on one L2.
// ---------------------------------------------------------------------------
template<int K>
__device__ __forceinline__ void conv_impl(
    const float* __restrict__ x, const float* __restrict__ wq,
    float* __restrict__ wlds, int groups,
    const float* __restrict__ gamma, const float* __restrict__ beta,
    const float* __restrict__ mean,  const float* __restrict__ var,
    const float* __restrict__ b1,    const float* __restrict__ slope,
    const float* __restrict__ b2,    float* __restrict__ out)
{
    constexpr int PAD = K / 2;
    const int tid  = threadIdx.x;
    const int lane = tid & 63;
    const int wv   = tid >> 6;

    // XCD-aware bijective swizzle: 65536 blocks = 8 XCDs * 8192
    const unsigned bid     = blockIdx.x;
    const unsigned logical = (bid & 7u) * 8192u + (bid >> 3);
    const int oc     = logical & 63;
    const int t2     = logical >> 6;
    const int rowblk = t2 & 63;
    const int b      = t2 >> 6;

    const int cing = CIN_ / groups;
    const int g    = oc / (COUT_ / groups);

    // stage this oc's (quantized) weights: cing*K*K floats
    const float* wsrc = wq + oc * CIN_ * K * K;
    for (int i = tid; i < cing * K * K; i += 256) wlds[i] = wsrc[i];
    __syncthreads();

    const int oh  = rowblk * 4 + wv;      // uniform per wave
    const int ih0 = oh * 2 - PAD;
    const int iwL = lane * 8;             // aligned input base (floats)

    float acc[4] = {0.f, 0.f, 0.f, 0.f};

    const float* xb = x + (size_t)(b * CIN_ + g * cing) * (H_ * W_);
    for (int ic = 0; ic < cing; ++ic) {
        const float* xc = xb + (size_t)ic * (H_ * W_);
        const float* wr = wlds + ic * (K * K);
#pragma unroll
        for (int r = 0; r < K; ++r) {
            const int ih = ih0 + r;
            if ((unsigned)ih < (unsigned)H_) {   // uniform branch per wave
                const float* xrow = xc + (size_t)ih * W_;
                float in[K + 6];
                const float4 v0 = *(const float4*)(xrow + iwL);
                const float4 v1 = *(const float4*)(xrow + iwL + 4);
                in[PAD + 0] = v0.x; in[PAD + 1] = v0.y;
                in[PAD + 2] = v0.z; in[PAD + 3] = v0.w;
                in[PAD + 4] = v1.x; in[PAD + 5] = v1.y;
                in[PAD + 6] = v1.z; in[PAD + 7] = v1.w;
#pragma unroll
                for (int e = 0; e < PAD; ++e) {            // left edge
                    const int iw = iwL - PAD + e;
                    in[e] = (iw >= 0) ? xrow[iw] : 0.f;
                }
#pragma unroll
                for (int e = 0; e < PAD - 1; ++e) {        // right edge
                    const int iw = iwL + 8 + e;
                    in[PAD + 8 + e] = (iw < W_) ? xrow[iw] : 0.f;
                }
#pragma unroll
                for (int s = 0; s < K; ++s) {
                    const float wv_ = wr[r * K + s];       // LDS broadcast
#pragma unroll
                    for (int j = 0; j < 4; ++j)
                        acc[j] = fmaf(in[2 * j + s], wv_, acc[j]);
                }
            }
        }
    }

    // fused epilogue: y = leaky(conv*A + C) + b2
    const float A  = gamma[oc] * rsqrtf(var[oc] + 1e-5f);
    const float Cc = beta[oc] - mean[oc] * A + b1[oc];
    const float sl = slope[oc];
    const float bb = b2[oc];
    float4 o; float y;
    y = fmaf(acc[0], A, Cc); y = (y >= 0.f) ? y : y * sl; o.x = y + bb;
    y = fmaf(acc[1], A, Cc); y = (y >= 0.f) ? y : y * sl; o.y = y + bb;
    y = fmaf(acc[2], A, Cc); y = (y >= 0.f) ? y : y * sl; o.z = y + bb;
    y = fmaf(acc[3], A, Cc); y = (y >= 0.f) ? y : y * sl; o.w = y + bb;

    float* op = out + ((size_t)((b * COUT_ + oc) * OH_ + oh)) * OW_ + lane * 4;
    *(float4*)op = o;
}

__global__ __launch_bounds__(256)
void conv_kernel(const float* __restrict__ x, const float* __restrict__ wq,
                 const int* __restrict__ sp,
                 const float* __restrict__ gamma, const float* __restrict__ beta,
                 const float* __restrict__ mean,  const float* __restrict__ var,
                 const float* __restrict__ b1,    const float* __restrict__ slope,
                 const float* __restrict__ b2,    float* __restrict__ out)
{
    __shared__ float wlds[CIN_ * KMAX_ * KMAX_];   // 784 floats, worst case
    const int k      = 3 + 2 * sp[1];
    const int groups = 1 + sp[2];
    if (k == 3)
        conv_impl<3>(x, wq, wlds, groups, gamma, beta, mean, var, b1, slope, b2, out);
    else if (k == 5)
        conv_impl<5>(x, wq, wlds, groups, gamma, beta, mean, var, b1, slope, b2, out);
    else
        conv_impl<7>(x, wq, wlds, groups, gamma, beta, mean, var, b1, slope, b2, out);
}

// ---------------------------------------------------------------------------
extern "C" void kernel_launch(void* const* d_in, const int* in_sizes, int n_in,
                              void* d_out, int out_size, void* d_ws, size_t ws_size,
                              hipStream_t stream)
{
    const float* x     = (const float*)d_in[0];
    const float* loss  = (const float*)d_in[1];
    const int*   sp    = (const int*)  d_in[2];
    const float* w     = (const float*)d_in[3];
    const float* gamma = (const float*)d_in[4];
    const float* beta  = (const float*)d_in[5];
    const float* mean  = (const float*)d_in[6];
    const float* var   = (const float*)d_in[7];
    const float* b1    = (const float*)d_in[8];
    const float* slope = (const float*)d_in[9];
    const float* b2    = (const float*)d_in[10];

    float* out = (float*)d_out;
    float* wq  = (float*)d_ws;   // up to 64*16*49 floats = 200 KB

    wprep_kernel<<<1, 1024, 0, stream>>>(w, loss, sp, wq, out + (out_size - 1));

    // B * COUT * OH/4 = 16 * 64 * 64 = 65536 blocks
    conv_kernel<<<65536, 256, 0, stream>>>(x, wq, sp, gamma, beta, mean, var,
                                           b1, slope, b2, out);
}

// Round 2
// 611.375 us; speedup vs baseline: 3.8971x; 3.8971x over previous
//
#include <hip/hip_runtime.h>

#define B_    16
#define CIN_  16
#define H_    512
#define W_    512
#define COUT_ 64
#define OH_   256
#define OW_   256
#define KMAX_ 7

// ---------------------------------------------------------------------------
// Kernel 1: weight slice absmax -> scale -> fake-quant into ws in layout
// [ic][r][s][oc]  (oc fastest: conv reads contiguous float4 per 4 oc),
// plus loss passthrough to d_out tail.
// ---------------------------------------------------------------------------
__global__ __launch_bounds__(1024)
void wprep_kernel(const float* __restrict__ w, const float* __restrict__ loss,
                  const int* __restrict__ sp, float* __restrict__ wq,
                  float* __restrict__ loss_out)
{
    const int k  = 3 + 2 * sp[1];          // KS_LIST = [3,5,7]
    const int s0 = (KMAX_ - k) >> 1;
    const int n  = COUT_ * CIN_ * k * k;

    float m = 0.f;
    for (int i = threadIdx.x; i < n; i += 1024) {
        int c = i % k; int t = i / k; int r = t % k; t /= k;
        int ic = t & (CIN_ - 1); int oc = t >> 4;
        float v = w[((oc * CIN_ + ic) * KMAX_ + s0 + r) * KMAX_ + s0 + c];
        m = fmaxf(m, fabsf(v));
    }
#pragma unroll
    for (int off = 32; off > 0; off >>= 1) m = fmaxf(m, __shfl_xor(m, off));

    __shared__ float sm[16];
    if ((threadIdx.x & 63) == 0) sm[threadIdx.x >> 6] = m;
    __syncthreads();
    if (threadIdx.x == 0) {
        float mm = sm[0];
#pragma unroll
        for (int i = 1; i < 16; ++i) mm = fmaxf(mm, sm[i]);
        sm[0] = mm / 127.0f;               // scale, IEEE div matches jax
    }
    __syncthreads();
    const float scale = sm[0];

    for (int i = threadIdx.x; i < n; i += 1024) {
        int c = i % k; int t = i / k; int r = t % k; t /= k;
        int ic = t & (CIN_ - 1); int oc = t >> 4;
        float v = w[((oc * CIN_ + ic) * KMAX_ + s0 + r) * KMAX_ + s0 + c];
        float q = rintf(v / scale);        // ties-to-even == jnp.round
        q = fminf(127.f, fmaxf(-127.f, q));
        wq[((ic * k + r) * k + c) * COUT_ + oc] = q * scale;
    }

    if (threadIdx.x == 0) loss_out[0] = loss[0];
}

// ---------------------------------------------------------------------------
// Kernel 2: direct conv (stride 2), register-blocked over 16 oc.
// Grid 4096 = 16 b x 64 rowblk x 4 ocg (ocg fastest for x reuse on one XCD).
// Block = 256 thr = 4 waves = 4 output rows; lane covers 4 ow; thread holds
// acc[16 oc][4 ow]. x strip (8+edge floats) in registers feeds 192 FMAs per
// (ic,row). Weights read as block-uniform contiguous float4 (scalar loads).
// ---------------------------------------------------------------------------
template<int K>
__device__ __forceinline__ void conv_impl(
    const float* __restrict__ x, const float* __restrict__ wq, int groups,
    const float* __restrict__ gamma, const float* __restrict__ beta,
    const float* __restrict__ mean,  const float* __restrict__ var,
    const float* __restrict__ b1,    const float* __restrict__ slope,
    const float* __restrict__ b2,    float* __restrict__ out)
{
    constexpr int PAD = K / 2;
    const int tid  = threadIdx.x;
    const int lane = tid & 63;
    const int wv   = tid >> 6;

    // bijective XCD swizzle: 4096 blocks = 8 XCDs * 512
    const unsigned bid     = blockIdx.x;
    const unsigned logical = (bid & 7u) * 512u + (bid >> 3);
    const int ocg    = logical & 3;        // fastest: 4 blocks share x rows
    const int rowblk = (logical >> 2) & 63;
    const int b      = logical >> 8;

    const int oc0  = ocg * 16;
    const int cing = CIN_ / groups;
    const int g    = oc0 / (COUT_ / groups);   // uniform across the 16 oc

    const int oh  = rowblk * 4 + wv;       // uniform per wave
    const int ih0 = oh * 2 - PAD;
    const int iwL = lane * 8;              // aligned input base (floats)

    float acc[16][4];
#pragma unroll
    for (int o = 0; o < 16; ++o)
#pragma unroll
        for (int j = 0; j < 4; ++j) acc[o][j] = 0.f;

    const float* xb = x + (size_t)(b * CIN_ + g * cing) * (H_ * W_);
    for (int ic = 0; ic < cing; ++ic) {
        const float* xc = xb + (size_t)ic * (H_ * W_);
#pragma unroll
        for (int r = 0; r < K; ++r) {
            const int ih = ih0 + r;
            if ((unsigned)ih < (unsigned)H_) {   // uniform branch per wave
                const float* xrow = xc + (size_t)ih * W_;
                float in[K + 6];
                const float4 v0 = *(const float4*)(xrow + iwL);
                const float4 v1 = *(const float4*)(xrow + iwL + 4);
                in[PAD + 0] = v0.x; in[PAD + 1] = v0.y;
                in[PAD + 2] = v0.z; in[PAD + 3] = v0.w;
                in[PAD + 4] = v1.x; in[PAD + 5] = v1.y;
                in[PAD + 6] = v1.z; in[PAD + 7] = v1.w;
#pragma unroll
                for (int e = 0; e < PAD; ++e) {            // left edge
                    const int iw = iwL - PAD + e;
                    in[e] = (iw >= 0) ? xrow[iw] : 0.f;
                }
#pragma unroll
                for (int e = 0; e < PAD - 1; ++e) {        // right edge
                    const int iw = iwL + 8 + e;
                    in[PAD + 8 + e] = (iw < W_) ? xrow[iw] : 0.f;
                }
                const float* wrr = wq + ((ic * K + r) * K) * COUT_ + oc0;
#pragma unroll
                for (int s = 0; s < K; ++s) {
                    const float* wrow = wrr + s * COUT_;   // block-uniform
#pragma unroll
                    for (int ocq = 0; ocq < 4; ++ocq) {
                        const float4 w4 = *(const float4*)(wrow + ocq * 4);
#pragma unroll
                        for (int j = 0; j < 4; ++j) {
                            acc[ocq * 4 + 0][j] = fmaf(in[2 * j + s], w4.x, acc[ocq * 4 + 0][j]);
                            acc[ocq * 4 + 1][j] = fmaf(in[2 * j + s], w4.y, acc[ocq * 4 + 1][j]);
                            acc[ocq * 4 + 2][j] = fmaf(in[2 * j + s], w4.z, acc[ocq * 4 + 2][j]);
                            acc[ocq * 4 + 3][j] = fmaf(in[2 * j + s], w4.w, acc[ocq * 4 + 3][j]);
                        }
                    }
                }
            }
        }
    }

    // fused epilogue: y = leaky(conv*A + C) + b2, per oc
#pragma unroll
    for (int o = 0; o < 16; ++o) {
        const int oc = oc0 + o;
        const float A  = gamma[oc] * rsqrtf(var[oc] + 1e-5f);
        const float Cc = beta[oc] - mean[oc] * A + b1[oc];
        const float sl = slope[oc];
        const float bb = b2[oc];
        float4 ov; float y;
        y = fmaf(acc[o][0], A, Cc); y = (y >= 0.f) ? y : y * sl; ov.x = y + bb;
        y = fmaf(acc[o][1], A, Cc); y = (y >= 0.f) ? y : y * sl; ov.y = y + bb;
        y = fmaf(acc[o][2], A, Cc); y = (y >= 0.f) ? y : y * sl; ov.z = y + bb;
        y = fmaf(acc[o][3], A, Cc); y = (y >= 0.f) ? y : y * sl; ov.w = y + bb;
        float* op = out + ((size_t)((b * COUT_ + oc) * OH_ + oh)) * OW_ + lane * 4;
        *(float4*)op = ov;
    }
}

__global__ __launch_bounds__(256)
void conv_kernel(const float* __restrict__ x, const float* __restrict__ wq,
                 const int* __restrict__ sp,
                 const float* __restrict__ gamma, const float* __restrict__ beta,
                 const float* __restrict__ mean,  const float* __restrict__ var,
                 const float* __restrict__ b1,    const float* __restrict__ slope,
                 const float* __restrict__ b2,    float* __restrict__ out)
{
    const int k      = 3 + 2 * sp[1];
    const int groups = 1 + sp[2];
    if (k == 3)
        conv_impl<3>(x, wq, groups, gamma, beta, mean, var, b1, slope, b2, out);
    else if (k == 5)
        conv_impl<5>(x, wq, groups, gamma, beta, mean, var, b1, slope, b2, out);
    else
        conv_impl<7>(x, wq, groups, gamma, beta, mean, var, b1, slope, b2, out);
}

// ---------------------------------------------------------------------------
extern "C" void kernel_launch(void* const* d_in, const int* in_sizes, int n_in,
                              void* d_out, int out_size, void* d_ws, size_t ws_size,
                              hipStream_t stream)
{
    const float* x     = (const float*)d_in[0];
    const float* loss  = (const float*)d_in[1];
    const int*   sp    = (const int*)  d_in[2];
    const float* w     = (const float*)d_in[3];
    const float* gamma = (const float*)d_in[4];
    const float* beta  = (const float*)d_in[5];
    const float* mean  = (const float*)d_in[6];
    const float* var   = (const float*)d_in[7];
    const float* b1    = (const float*)d_in[8];
    const float* slope = (const float*)d_in[9];
    const float* b2    = (const float*)d_in[10];

    float* out = (float*)d_out;
    float* wq  = (float*)d_ws;   // up to 64*16*49 floats = 200 KB

    wprep_kernel<<<1, 1024, 0, stream>>>(w, loss, sp, wq, out + (out_size - 1));

    // 16 b * 64 rowblk * 4 ocg = 4096 blocks
    conv_kernel<<<4096, 256, 0, stream>>>(x, wq, sp, gamma, beta, mean, var,
                                          b1, slope, b2, out);
}

// Round 6
// 558.226 us; speedup vs baseline: 4.2681x; 1.0952x over previous
//
#include <hip/hip_runtime.h>

#define B_    16
#define CIN_  16
#define HW_   512
#define COUT_ 64
#define OHW_  256

typedef __attribute__((ext_vector_type(8))) short bf16x8;
typedef __attribute__((ext_vector_type(4))) float f32x4;

__device__ __forceinline__ ushort f2bf(float f){
    unsigned u = __float_as_uint(f);
    return (ushort)((u + 0x7fffu + ((u >> 16) & 1u)) >> 16);   // RNE, finite inputs
}

// ---------------------------------------------------------------------------
// wprep 1: absmax over the sliced window (flat [oc][ic][7][7], mask r,c)
// ---------------------------------------------------------------------------
__global__ __launch_bounds__(256)
void absmax_k(const float* __restrict__ w, const int* __restrict__ sp,
              unsigned* __restrict__ smax)
{
    const int ks = 3 + 2 * sp[1];
    const int s0 = (7 - ks) >> 1, s1 = s0 + ks;
    float m = 0.f;
    for (int i = blockIdx.x * 256 + threadIdx.x; i < 64*16*49; i += gridDim.x * 256){
        int c7 = i % 7, t = i / 7;
        int r7 = t % 7;
        if (c7 >= s0 && c7 < s1 && r7 >= s0 && r7 < s1)
            m = fmaxf(m, fabsf(w[i]));
    }
#pragma unroll
    for (int off = 32; off; off >>= 1) m = fmaxf(m, __shfl_xor(m, off));
    __shared__ float sm[4];
    if ((threadIdx.x & 63) == 0) sm[threadIdx.x >> 6] = m;
    __syncthreads();
    if (threadIdx.x == 0){
        m = fmaxf(fmaxf(sm[0], sm[1]), fmaxf(sm[2], sm[3]));
        atomicMax(smax, __float_as_uint(m));   // values >= +0 -> int order ok
    }
}

// ---------------------------------------------------------------------------
// wprep 2: fake-quant + bf16 + layout [oc][KPAD] (zero K-pad), loss copy
// ---------------------------------------------------------------------------
__global__ __launch_bounds__(256)
void quant_k(const float* __restrict__ w, const int* __restrict__ sp,
             const unsigned* __restrict__ smax, const float* __restrict__ loss,
             ushort* __restrict__ wq, float* __restrict__ loss_out)
{
    const int ks = 3 + 2 * sp[1];
    const int s0 = (7 - ks) >> 1;
    const int ks2 = ks * ks;
    const int K_REAL = 16 * ks2;
    const int KPAD = ((K_REAL + 31) >> 5) << 5;
    const float scale = __uint_as_float(*smax) / 127.0f;
    const int total = 64 * KPAD;
    for (int i = blockIdx.x * 256 + threadIdx.x; i < total; i += gridDim.x * 256){
        int oc = i / KPAD, k = i - oc * KPAD;
        ushort v = 0;
        if (k < K_REAL){
            int ic = k / ks2, rem = k - ic * ks2;
            int r = rem / ks, s = rem - r * ks;
            float wv = w[((oc * 16 + ic) * 7 + s0 + r) * 7 + s0 + s];
            float q = rintf(wv / scale);               // ties-to-even
            q = fminf(127.f, fmaxf(-127.f, q));
            v = f2bf(q * scale);
        }
        wq[i] = v;
    }
    if (blockIdx.x == 0 && threadIdx.x == 0) loss_out[0] = loss[0];
}

// ---------------------------------------------------------------------------
// conv: implicit GEMM, C[64 oc][OWB ow] per block via mfma_f32_16x16x32_bf16.
// B staged in LDS as [chunk=k/8][col][8 k] bf16: frag read = 1 coalesced
// ds_read_b128, conflict-free. A (weights) read from global (L1-hot 20KB).
// 4 waves; wave = one 16-oc tile x all ow tiles. One fill + 1 barrier.
// ---------------------------------------------------------------------------
template<int KS, int OWB>
__global__ __launch_bounds__(256, 4)
void conv_mfma(const float* __restrict__ x, const ushort* __restrict__ wq,
               const int* __restrict__ sp,
               const float* __restrict__ gamma, const float* __restrict__ beta,
               const float* __restrict__ mean,  const float* __restrict__ var,
               const float* __restrict__ b1,    const float* __restrict__ slope,
               const float* __restrict__ b2,    float* __restrict__ out)
{
    constexpr int PAD     = KS / 2;
    constexpr int K_REAL  = 16 * KS * KS;
    constexpr int KSTEPS  = (K_REAL + 31) / 32;
    constexpr int KPAD    = KSTEPS * 32;
    constexpr int CH_TOT  = KPAD / 8;        // 16B chunks per col
    constexpr int CH_REAL = K_REAL / 8;      // exact (16*KS^2 % 8 == 0)
    constexpr int CROW    = OWB * 8;         // ushorts per chunk row
    constexpr int NT      = OWB / 16;        // n-tiles
    constexpr int NOW     = 256 / OWB;       // ow-groups per output row

    __shared__ __align__(16) ushort Blds[CH_TOT * CROW];

    if (3 + 2 * sp[1] != KS) return;         // runtime ksize dispatch

    const int tid = threadIdx.x, lane = tid & 63, wv = tid >> 6;

    // bijective XCD swizzle; within an XCD: owg fastest, then oh (row reuse)
    const unsigned nlog = (unsigned)(B_ * 256 * NOW) / 8u;
    const unsigned logical = (blockIdx.x & 7u) * nlog + (blockIdx.x >> 3);
    const int owg = logical & (NOW - 1);
    const int oh  = (logical / NOW) & 255;
    const int b   = logical / (NOW * 256);
    const int ow0 = owg * OWB;

    // ---- fill B (im2col, bf16) ----
    if constexpr (KS == 3){
        // wave wv: ic 4wv..4wv+3 -> k [36wv, 36wv+36); lane = col
        ushort arr[36];
        const int base = 2 * ow0;
#pragma unroll
        for (int il = 0; il < 4; ++il){
            const int ic = wv * 4 + il;
            const float* xpl = x + (size_t)(b * CIN_ + ic) * (HW_ * HW_);
#pragma unroll
            for (int r = 0; r < 3; ++r){
                const int ih = 2 * oh + r - 1;
                const int kl = il * 9 + r * 3;
                if ((unsigned)ih < (unsigned)HW_){
                    const float* xrow = xpl + (size_t)ih * HW_;
                    const int i0 = base + 2 * lane;
                    const float2 eo = *(const float2*)(xrow + i0);   // s=1,2
                    const float prev = (i0 > 0) ? xrow[i0 - 1] : 0.f; // s=0
                    arr[kl + 0] = f2bf(prev);
                    arr[kl + 1] = f2bf(eo.x);
                    arr[kl + 2] = f2bf(eo.y);
                } else {
                    arr[kl + 0] = 0; arr[kl + 1] = 0; arr[kl + 2] = 0;
                }
            }
        }
#pragma unroll
        for (int uu = 0; uu < 9; ++uu){      // 9 x ds_write_b64, conflict-free
            const int u = wv * 9 + uu;       // b64 unit = 4 k's
            ushort4 v = make_ushort4(arr[4*uu], arr[4*uu+1], arr[4*uu+2], arr[4*uu+3]);
            *(ushort4*)(Blds + (u >> 1) * CROW + lane * 8 + (u & 1) * 4) = v;
        }
    } else {
        // generic (never exercised for this input): col-gather
        constexpr int ks2 = KS * KS;
        constexpr int kperw = K_REAL / 4;
        const float* xb = x + (size_t)b * CIN_ * HW_ * HW_;
        if (lane < OWB){
            for (int kk = wv * kperw; kk < (wv + 1) * kperw; ++kk){
                int ic = kk / ks2, rem = kk - ic * ks2;
                int r = rem / KS, s = rem - r * KS;
                int ih = 2 * oh + r - PAD;
                int iw = 2 * (ow0 + lane) + s - PAD;
                float v = 0.f;
                if ((unsigned)ih < (unsigned)HW_ && (unsigned)iw < (unsigned)HW_)
                    v = xb[((size_t)ic * HW_ + ih) * HW_ + iw];
                Blds[(kk >> 3) * CROW + lane * 8 + (kk & 7)] = f2bf(v);
            }
        }
    }
    if (wv == 0 && lane < OWB){              // zero K-pad chunks (A pad also 0)
        const ushort4 z = make_ushort4(0, 0, 0, 0);
#pragma unroll
        for (int ch = CH_REAL; ch < CH_TOT; ++ch){
            *(ushort4*)(Blds + ch * CROW + lane * 8)     = z;
            *(ushort4*)(Blds + ch * CROW + lane * 8 + 4) = z;
        }
    }
    __syncthreads();

    // ---- MFMA: D[row=oc][col=ow]; lane: col=lane&15, k-chunk=(lane>>4)*8 ----
    const int cl = lane & 15, q = lane >> 4;
    f32x4 acc[NT];
#pragma unroll
    for (int n = 0; n < NT; ++n) acc[n] = (f32x4){0.f, 0.f, 0.f, 0.f};

    const ushort* arow = wq + (size_t)(wv * 16 + cl) * KPAD;
#pragma unroll
    for (int kst = 0; kst < KSTEPS; ++kst){
        const bf16x8 af = *(const bf16x8*)(arow + kst * 32 + q * 8);
#pragma unroll
        for (int n = 0; n < NT; ++n){
            const bf16x8 bf = *(const bf16x8*)(Blds + (kst * 4 + q) * CROW + (n * 16 + cl) * 8);
            acc[n] = __builtin_amdgcn_mfma_f32_16x16x32_bf16(af, bf, acc[n], 0, 0, 0);
        }
    }

    // ---- fused epilogue: y = leaky(conv*A + C) + b2 ----
    const int ocb = wv * 16 + q * 4;         // C/D row = q*4 + reg
    float A_[4], C_[4], S_[4], B2_[4];
#pragma unroll
    for (int j = 0; j < 4; ++j){
        const int oc = ocb + j;
        const float a = gamma[oc] * (1.0f / sqrtf(var[oc] + 1e-5f));
        A_[j]  = a;
        C_[j]  = beta[oc] - mean[oc] * a + b1[oc];
        S_[j]  = slope[oc];
        B2_[j] = b2[oc];
    }
#pragma unroll
    for (int n = 0; n < NT; ++n){
#pragma unroll
        for (int j = 0; j < 4; ++j){
            float y = fmaf(acc[n][j], A_[j], C_[j]);
            y = (y >= 0.f) ? y : y * S_[j];
            const int oc = ocb + j;
            out[(((size_t)(b * COUT_ + oc)) * OHW_ + oh) * OHW_ + ow0 + n * 16 + cl] = y + B2_[j];
        }
    }
}

// ---------------------------------------------------------------------------
extern "C" void kernel_launch(void* const* d_in, const int* in_sizes, int n_in,
                              void* d_out, int out_size, void* d_ws, size_t ws_size,
                              hipStream_t stream)
{
    const float* x     = (const float*)d_in[0];
    const float* loss  = (const float*)d_in[1];
    const int*   sp    = (const int*)  d_in[2];
    const float* w     = (const float*)d_in[3];
    const float* gamma = (const float*)d_in[4];
    const float* beta  = (const float*)d_in[5];
    const float* mean  = (const float*)d_in[6];
    const float* var   = (const float*)d_in[7];
    const float* b1    = (const float*)d_in[8];
    const float* slope = (const float*)d_in[9];
    const float* b2    = (const float*)d_in[10];

    float*    out  = (float*)d_out;
    unsigned* smax = (unsigned*)d_ws;
    ushort*   wq   = (ushort*)((char*)d_ws + 256);   // up to 64*800*2 = 100KB

    hipMemsetAsync(smax, 0, 4, stream);
    absmax_k<<<64, 256, 0, stream>>>(w, sp, smax);
    quant_k<<<200, 256, 0, stream>>>(w, sp, smax, loss, wq, out + (out_size - 1));

    // grid = B * 256 oh * (256/OWB); only the sp-matching kernel does work
    conv_mfma<3, 64><<<16384, 256, 0, stream>>>(x, wq, sp, gamma, beta, mean, var, b1, slope, b2, out);
    conv_mfma<5, 64><<<16384, 256, 0, stream>>>(x, wq, sp, gamma, beta, mean, var, b1, slope, b2, out);
    conv_mfma<7, 32><<<32768, 256, 0, stream>>>(x, wq, sp, gamma, beta, mean, var, b1, slope, b2, out);
}